// Round 1
// baseline (315.756 us; speedup 1.0000x reference)
//
#include <hip/hip_runtime.h>
#include <hip/hip_bf16.h>
#include <math.h>
#include <stdint.h>

#define S_ 4096
#define H_ 1024
#define NH_ 16
#define HD_ 64
#define LOG2E 1.4426950408889634f

typedef __bf16 bf16;
typedef __attribute__((ext_vector_type(8))) __bf16 bf16x8;
typedef __attribute__((ext_vector_type(4))) __bf16 bf16x4;
typedef __attribute__((ext_vector_type(4))) float f32x4;

__device__ __forceinline__ f32x4 mfma16(bf16x8 a, bf16x8 b, f32x4 c) {
    return __builtin_amdgcn_mfma_f32_16x16x32_bf16(a, b, c, 0, 0, 0);
}

// async global->LDS, 16B per lane. LDS dest must be the wave-uniform base;
// HW places lane i at base + i*16 (guide §5). Casts via uintptr_t (CK idiom).
__device__ __forceinline__ void gload16(const void* g, void* l) {
    __builtin_amdgcn_global_load_lds(
        (__attribute__((address_space(1))) void*)(uintptr_t)g,
        (__attribute__((address_space(3))) void*)(uintptr_t)l,
        16, 0, 0);
}

// ---------------- f32 -> bf16 conversion (8 elems/thread) ----------------
__global__ __launch_bounds__(256) void cvt_kernel(const float* __restrict__ src,
                                                  bf16* __restrict__ dst, int n) {
    int i = (blockIdx.x * 256 + threadIdx.x) * 8;
    if (i >= n) return;
    float4 v0 = *reinterpret_cast<const float4*>(src + i);
    float4 v1 = *reinterpret_cast<const float4*>(src + i + 4);
    bf16x8 o;
    o[0] = (bf16)v0.x; o[1] = (bf16)v0.y; o[2] = (bf16)v0.z; o[3] = (bf16)v0.w;
    o[4] = (bf16)v1.x; o[5] = (bf16)v1.y; o[6] = (bf16)v1.z; o[7] = (bf16)v1.w;
    *reinterpret_cast<bf16x8*>(dst + i) = o;
}

// ---------------- RoPE cos/sin table, f64 for range-reduction accuracy ----
__global__ __launch_bounds__(256) void rope_table_kernel(float2* __restrict__ tab) {
    int idx = blockIdx.x * 256 + threadIdx.x;
    if (idx >= S_ * 32) return;
    int i = idx & 31, s = idx >> 5;
    double ang = (double)s * exp(-(double)(2 * i) / 64.0 * log(10000.0));
    tab[idx] = make_float2((float)cos(ang), (float)sin(ang));
}

// ---------------- QKV GEMM: C[m,n] = sum_k X[m,k] * W[n,k] + b[n] ---------
// 128x128 tile, BK=64, 4 waves (each 64x64 = 4x4 frags of 16x16x32 MFMA).
// z=0 -> Q [S,H], z=1 -> K [S,H], z=2 -> V stored transposed Vt [H,S].
__global__ __launch_bounds__(256) void qkv_gemm_kernel(
    const bf16* __restrict__ Xb,
    const bf16* __restrict__ Wqb, const bf16* __restrict__ Wkb, const bf16* __restrict__ Wvb,
    const float* __restrict__ bqp, const float* __restrict__ bkp, const float* __restrict__ bvp,
    bf16* __restrict__ Qo, bf16* __restrict__ Ko, bf16* __restrict__ Vto)
{
    __shared__ bf16 Alds[128 * 64];
    __shared__ bf16 Blds[128 * 64];
    const int z = blockIdx.z;
    const bf16* W = z == 0 ? Wqb : z == 1 ? Wkb : Wvb;
    const float* bias = z == 0 ? bqp : z == 1 ? bkp : bvp;
    const int tm = blockIdx.y * 128, tn = blockIdx.x * 128;
    const int tid = threadIdx.x, lane = tid & 63, wid = tid >> 6;
    const int wm = (wid >> 1) * 64, wn = (wid & 1) * 64;
    const int lr = lane & 15, lg = lane >> 4;
    const int c_row = tid >> 3, c_sub = tid & 7;   // staging chunk coords

    f32x4 acc[4][4] = {};

    for (int kt = 0; kt < H_; kt += 64) {
        // stage A[128][64] and B[128][64]; XOR-swizzle the GLOBAL source
        // chunk so the linear LDS layout reads conflict-light (rule #21).
        #pragma unroll
        for (int is = 0; is < 4; ++is) {
            int row = is * 32 + c_row;
            int sub = c_sub ^ (row & 7);
            gload16(&Xb[(size_t)(tm + row) * H_ + kt + sub * 8],
                    &Alds[(is * 256 + wid * 64) * 8]);
            gload16(&W[(size_t)(tn + row) * H_ + kt + sub * 8],
                    &Blds[(is * 256 + wid * 64) * 8]);
        }
        __syncthreads();

        #pragma unroll
        for (int kc = 0; kc < 2; ++kc) {
            bf16x8 af[4], bfr[4];
            #pragma unroll
            for (int mb = 0; mb < 4; ++mb) {
                int row = wm + mb * 16 + lr;
                int ch = (kc * 4 + lg) ^ (row & 7);
                af[mb] = *reinterpret_cast<const bf16x8*>(&Alds[row * 64 + ch * 8]);
            }
            #pragma unroll
            for (int nb = 0; nb < 4; ++nb) {
                int row = wn + nb * 16 + lr;
                int ch = (kc * 4 + lg) ^ (row & 7);
                bfr[nb] = *reinterpret_cast<const bf16x8*>(&Blds[row * 64 + ch * 8]);
            }
            #pragma unroll
            for (int mb = 0; mb < 4; ++mb)
                #pragma unroll
                for (int nb = 0; nb < 4; ++nb)
                    acc[mb][nb] = mfma16(af[mb], bfr[nb], acc[mb][nb]);
        }
        __syncthreads();
    }

    float bv4[4];
    #pragma unroll
    for (int nb = 0; nb < 4; ++nb) bv4[nb] = bias[tn + wn + nb * 16 + lr];

    if (z < 2) {
        bf16* Y = z == 0 ? Qo : Ko;
        #pragma unroll
        for (int mb = 0; mb < 4; ++mb)
            #pragma unroll
            for (int nb = 0; nb < 4; ++nb) {
                int col = tn + wn + nb * 16 + lr;
                #pragma unroll
                for (int r = 0; r < 4; ++r) {
                    int row = tm + wm + mb * 16 + lg * 4 + r;
                    Y[(size_t)row * H_ + col] = (bf16)(acc[mb][nb][r] + bv4[nb]);
                }
            }
    } else {
        // Vt[n][m]: 4 consecutive rows (m) per lane -> one 8B store
        #pragma unroll
        for (int mb = 0; mb < 4; ++mb) {
            int rowb = tm + wm + mb * 16 + lg * 4;
            #pragma unroll
            for (int nb = 0; nb < 4; ++nb) {
                int col = tn + wn + nb * 16 + lr;
                bf16x4 pk;
                #pragma unroll
                for (int r = 0; r < 4; ++r) pk[r] = (bf16)(acc[mb][nb][r] + bv4[nb]);
                *reinterpret_cast<bf16x4*>(&Vto[(size_t)col * S_ + rowb]) = pk;
            }
        }
    }
}

// ---------------- RoPE in place on Q and K (pair d, d+32) -----------------
__global__ __launch_bounds__(256) void rope_kernel(bf16* __restrict__ Q,
                                                   bf16* __restrict__ K,
                                                   const float2* __restrict__ tab) {
    int t = blockIdx.x * 256 + threadIdx.x;   // 2 * 4096 * 16 * 32 = 2^22
    int i = t & 31;
    int h = (t >> 5) & 15;
    int s = (t >> 9) & 4095;
    int which = t >> 21;
    bf16* P = which ? K : Q;
    float2 cs = tab[(s << 5) + i];
    size_t base = ((size_t)s << 10) + (h << 6) + i;
    float x1 = (float)P[base], x2 = (float)P[base + 32];
    P[base]      = (bf16)(x1 * cs.x - x2 * cs.y);
    P[base + 32] = (bf16)(x2 * cs.x + x1 * cs.y);
}

// ---------------- Flash attention: 64 q / block, 4 waves x 16 q -----------
__global__ __launch_bounds__(256) void attn_kernel(
    const bf16* __restrict__ Q, const bf16* __restrict__ K, const bf16* __restrict__ Vt,
    const float* __restrict__ mask, float* __restrict__ out)
{
    __shared__ bf16 Klds[64 * 64];
    __shared__ bf16 Vlds[64 * 64];
    __shared__ bf16 Plds[4][16][72];   // +8 pad breaks bank aliasing on A-frag reads
    const int h = blockIdx.y;
    const int qb = blockIdx.x * 64;
    const int tid = threadIdx.x, lane = tid & 63, wid = tid >> 6;
    const int lr = lane & 15, lg = lane >> 4;
    const int c_row = tid >> 3, c_sub = tid & 7;

    // Q fragments live in registers for the whole kernel
    bf16x8 qf[2];
    const int qrow = qb + wid * 16 + lr;
    #pragma unroll
    for (int c = 0; c < 2; ++c)
        qf[c] = *reinterpret_cast<const bf16x8*>(
            &Q[(size_t)qrow * H_ + h * 64 + c * 32 + lg * 8]);

    f32x4 acc[4] = {};
    float m_r[4], l_r[4];
    #pragma unroll
    for (int r = 0; r < 4; ++r) { m_r[r] = -INFINITY; l_r[r] = 0.f; }

    for (int kb = 0; kb < S_; kb += 64) {
        // stage K[64 keys][64 hd] and Vt[64 hd][64 keys], source-swizzled
        #pragma unroll
        for (int is = 0; is < 2; ++is) {
            int row = is * 32 + c_row;
            int sub = c_sub ^ (row & 7);
            gload16(&K[(size_t)(kb + row) * H_ + h * 64 + sub * 8],
                    &Klds[(is * 256 + wid * 64) * 8]);
            gload16(&Vt[(size_t)(h * 64 + row) * S_ + kb + sub * 8],
                    &Vlds[(is * 256 + wid * 64) * 8]);
        }
        __syncthreads();

        // S = Q K^T  (M=16 q, N=64 keys, K=64 hd)
        f32x4 sf[4] = {};
        #pragma unroll
        for (int nb = 0; nb < 4; ++nb)
            #pragma unroll
            for (int c = 0; c < 2; ++c) {
                int row = nb * 16 + lr;
                int ch = (c * 4 + lg) ^ (row & 7);
                bf16x8 kf = *reinterpret_cast<const bf16x8*>(&Klds[row * 64 + ch * 8]);
                sf[nb] = mfma16(qf[c], kf, sf[nb]);
            }

        // scale + mask; rows owned by this lane: lg*4 + r
        float sv[4][4];
        #pragma unroll
        for (int nb = 0; nb < 4; ++nb) {
            float mv = mask[kb + nb * 16 + lr];
            #pragma unroll
            for (int r = 0; r < 4; ++r) sv[nb][r] = sf[nb][r] * 0.125f + mv;
        }
        // row max over 64 keys: in-lane over nb, then xor-shuffle over 16 lanes
        float pmax[4];
        #pragma unroll
        for (int r = 0; r < 4; ++r)
            pmax[r] = fmaxf(fmaxf(sv[0][r], sv[1][r]), fmaxf(sv[2][r], sv[3][r]));
        #pragma unroll
        for (int off = 1; off < 16; off <<= 1)
            #pragma unroll
            for (int r = 0; r < 4; ++r)
                pmax[r] = fmaxf(pmax[r], __shfl_xor(pmax[r], off, 64));

        float corr[4], psum[4];
        #pragma unroll
        for (int r = 0; r < 4; ++r) {
            float mn = fmaxf(m_r[r], pmax[r]);
            corr[r] = exp2f((m_r[r] - mn) * LOG2E);
            m_r[r] = mn;
            psum[r] = 0.f;
        }
        #pragma unroll
        for (int nb = 0; nb < 4; ++nb)
            #pragma unroll
            for (int r = 0; r < 4; ++r) {
                float p = exp2f((sv[nb][r] - m_r[r]) * LOG2E);
                psum[r] += p;
                Plds[wid][lg * 4 + r][nb * 16 + lr] = (bf16)p;  // wave-local
            }
        #pragma unroll
        for (int off = 1; off < 16; off <<= 1)
            #pragma unroll
            for (int r = 0; r < 4; ++r)
                psum[r] += __shfl_xor(psum[r], off, 64);
        #pragma unroll
        for (int r = 0; r < 4; ++r) l_r[r] = l_r[r] * corr[r] + psum[r];
        #pragma unroll
        for (int nb = 0; nb < 4; ++nb) {
            f32x4 a = acc[nb];
            a[0] *= corr[0]; a[1] *= corr[1]; a[2] *= corr[2]; a[3] *= corr[3];
            acc[nb] = a;
        }

        // O += P V  (A = P from wave-local LDS, B = V^T tile)
        bf16x8 pa[2];
        #pragma unroll
        for (int c = 0; c < 2; ++c)
            pa[c] = *reinterpret_cast<const bf16x8*>(&Plds[wid][lr][c * 32 + lg * 8]);
        #pragma unroll
        for (int nb = 0; nb < 4; ++nb)
            #pragma unroll
            for (int c = 0; c < 2; ++c) {
                int row = nb * 16 + lr;
                int ch = (c * 4 + lg) ^ (row & 7);
                bf16x8 vf = *reinterpret_cast<const bf16x8*>(&Vlds[row * 64 + ch * 8]);
                acc[nb] = mfma16(pa[c], vf, acc[nb]);
            }
        __syncthreads();   // K/V LDS consumed; safe to restage next iter
    }

    #pragma unroll
    for (int r = 0; r < 4; ++r) {
        float inv = 1.f / l_r[r];
        int row = qb + wid * 16 + lg * 4 + r;
        #pragma unroll
        for (int nb = 0; nb < 4; ++nb)
            out[(size_t)row * H_ + h * 64 + nb * 16 + lr] = acc[nb][r] * inv;
    }
}

extern "C" void kernel_launch(void* const* d_in, const int* in_sizes, int n_in,
                              void* d_out, int out_size, void* d_ws, size_t ws_size,
                              hipStream_t stream) {
    const float* hs   = (const float*)d_in[0];
    const float* mask = (const float*)d_in[1];
    const float* Wq   = (const float*)d_in[2];
    const float* bq   = (const float*)d_in[3];
    const float* Wk   = (const float*)d_in[4];
    const float* bk   = (const float*)d_in[5];
    const float* Wv   = (const float*)d_in[6];
    const float* bv   = (const float*)d_in[7];
    float* out = (float*)d_out;

    char* ws = (char*)d_ws;
    bf16* Xb   = (bf16*)(ws);                  // 8 MB  [S,H]
    bf16* Wqb  = (bf16*)(ws + (8u  << 20));    // 2 MB
    bf16* Wkb  = (bf16*)(ws + (10u << 20));    // 2 MB
    bf16* Wvb  = (bf16*)(ws + (12u << 20));    // 2 MB
    bf16* Qb   = (bf16*)(ws + (14u << 20));    // 8 MB  [S,H]
    bf16* Kb   = (bf16*)(ws + (22u << 20));    // 8 MB  [S,H]
    bf16* Vt   = (bf16*)(ws + (30u << 20));    // 8 MB  [H,S]
    float2* tab = (float2*)(ws + (38u << 20)); // 1 MB  [S,32] (cos,sin)

    cvt_kernel<<<S_ * H_ / 2048, 256, 0, stream>>>(hs, Xb, S_ * H_);
    cvt_kernel<<<H_ * H_ / 2048, 256, 0, stream>>>(Wq, Wqb, H_ * H_);
    cvt_kernel<<<H_ * H_ / 2048, 256, 0, stream>>>(Wk, Wkb, H_ * H_);
    cvt_kernel<<<H_ * H_ / 2048, 256, 0, stream>>>(Wv, Wvb, H_ * H_);
    rope_table_kernel<<<(S_ * 32) / 256, 256, 0, stream>>>(tab);
    qkv_gemm_kernel<<<dim3(H_ / 128, S_ / 128, 3), 256, 0, stream>>>(
        Xb, Wqb, Wkb, Wvb, bq, bk, bv, Qb, Kb, Vt);
    rope_kernel<<<(2 * S_ * NH_ * 32) / 256, 256, 0, stream>>>(Qb, Kb, tab);
    attn_kernel<<<dim3(S_ / 64, NH_), 256, 0, stream>>>(Qb, Kb, Vt, mask, out);
}

// Round 2
// 229.696 us; speedup vs baseline: 1.3747x; 1.3747x over previous
//
#include <hip/hip_runtime.h>
#include <hip/hip_bf16.h>
#include <math.h>
#include <stdint.h>

#define S_ 4096
#define H_ 1024
#define NH_ 16
#define HD_ 64
#define LOG2E 1.4426950408889634f
#define QSCALE (0.125f * LOG2E)

typedef __bf16 bf16;
typedef __attribute__((ext_vector_type(8))) __bf16 bf16x8;
typedef __attribute__((ext_vector_type(4))) __bf16 bf16x4;
typedef __attribute__((ext_vector_type(4))) float f32x4;
typedef __attribute__((ext_vector_type(16))) float f32x16;
typedef __attribute__((ext_vector_type(2))) int int2v;

__device__ __forceinline__ f32x4 mfma16(bf16x8 a, bf16x8 b, f32x4 c) {
    return __builtin_amdgcn_mfma_f32_16x16x32_bf16(a, b, c, 0, 0, 0);
}
__device__ __forceinline__ f32x16 mfma32(bf16x8 a, bf16x8 b, f32x16 c) {
    return __builtin_amdgcn_mfma_f32_32x32x16_bf16(a, b, c, 0, 0, 0);
}

// async global->LDS, 16B per lane; LDS dest = wave-uniform base + lane*16.
__device__ __forceinline__ void gload16(const void* g, void* l) {
    __builtin_amdgcn_global_load_lds(
        (__attribute__((address_space(1))) void*)(uintptr_t)g,
        (__attribute__((address_space(3))) void*)(uintptr_t)l,
        16, 0, 0);
}

// pack two f32 -> one u32 of 2 bf16 (lo = a, hi = b)
__device__ __forceinline__ unsigned cvtpk(float a, float b) {
    unsigned r;
    asm("v_cvt_pk_bf16_f32 %0, %1, %2" : "=v"(r) : "v"(a), "v"(b));
    return r;
}

// (r0, r1) = (concat(a_lo, b_lo), concat(a_hi, b_hi)) across the 32-lane halves
__device__ __forceinline__ void swap32(unsigned a, unsigned b, unsigned& r0, unsigned& r1) {
#if __has_builtin(__builtin_amdgcn_permlane32_swap)
    int2v rr = __builtin_amdgcn_permlane32_swap((int)a, (int)b, false, false);
    r0 = (unsigned)rr[0];
    r1 = (unsigned)rr[1];
#else
    unsigned sa = (unsigned)__shfl_xor((int)a, 32, 64);
    unsigned sb = (unsigned)__shfl_xor((int)b, 32, 64);
    bool hi = (threadIdx.x & 32) != 0;
    r0 = hi ? sb : a;
    r1 = hi ? b : sa;
#endif
}

// ---------------- f32 -> bf16 conversion (8 elems/thread) ----------------
__global__ __launch_bounds__(256) void cvt_kernel(const float* __restrict__ src,
                                                  bf16* __restrict__ dst, int n) {
    int i = (blockIdx.x * 256 + threadIdx.x) * 8;
    if (i >= n) return;
    float4 v0 = *reinterpret_cast<const float4*>(src + i);
    float4 v1 = *reinterpret_cast<const float4*>(src + i + 4);
    bf16x8 o;
    o[0] = (bf16)v0.x; o[1] = (bf16)v0.y; o[2] = (bf16)v0.z; o[3] = (bf16)v0.w;
    o[4] = (bf16)v1.x; o[5] = (bf16)v1.y; o[6] = (bf16)v1.z; o[7] = (bf16)v1.w;
    *reinterpret_cast<bf16x8*>(dst + i) = o;
}

// ---------------- RoPE cos/sin table, f64 for range-reduction accuracy ----
__global__ __launch_bounds__(256) void rope_table_kernel(float2* __restrict__ tab) {
    int idx = blockIdx.x * 256 + threadIdx.x;
    if (idx >= S_ * 32) return;
    int i = idx & 31, s = idx >> 5;
    double ang = (double)s * exp(-(double)(2 * i) / 64.0 * log(10000.0));
    tab[idx] = make_float2((float)cos(ang), (float)sin(ang));
}

// ---------------- maskL = mask * log2(e) ---------------------------------
__global__ __launch_bounds__(256) void maskl_kernel(const float* __restrict__ mask,
                                                    float* __restrict__ maskL) {
    int i = blockIdx.x * 256 + threadIdx.x;
    if (i < S_) maskL[i] = mask[i] * LOG2E;
}

// ---------------- QKV GEMM: C[m,n] = sum_k X[m,k] * W[n,k] + b[n] ---------
__global__ __launch_bounds__(256) void qkv_gemm_kernel(
    const bf16* __restrict__ Xb,
    const bf16* __restrict__ Wqb, const bf16* __restrict__ Wkb, const bf16* __restrict__ Wvb,
    const float* __restrict__ bqp, const float* __restrict__ bkp, const float* __restrict__ bvp,
    bf16* __restrict__ Qo, bf16* __restrict__ Ko, bf16* __restrict__ Vto)
{
    __shared__ bf16 Alds[128 * 64];
    __shared__ bf16 Blds[128 * 64];
    const int z = blockIdx.z;
    const bf16* W = z == 0 ? Wqb : z == 1 ? Wkb : Wvb;
    const float* bias = z == 0 ? bqp : z == 1 ? bkp : bvp;
    const int tm = blockIdx.y * 128, tn = blockIdx.x * 128;
    const int tid = threadIdx.x, lane = tid & 63, wid = tid >> 6;
    const int wm = (wid >> 1) * 64, wn = (wid & 1) * 64;
    const int lr = lane & 15, lg = lane >> 4;
    const int c_row = tid >> 3, c_sub = tid & 7;

    f32x4 acc[4][4] = {};

    for (int kt = 0; kt < H_; kt += 64) {
        #pragma unroll
        for (int is = 0; is < 4; ++is) {
            int row = is * 32 + c_row;
            int sub = c_sub ^ (row & 7);
            gload16(&Xb[(size_t)(tm + row) * H_ + kt + sub * 8],
                    &Alds[(is * 256 + wid * 64) * 8]);
            gload16(&W[(size_t)(tn + row) * H_ + kt + sub * 8],
                    &Blds[(is * 256 + wid * 64) * 8]);
        }
        __syncthreads();

        #pragma unroll
        for (int kc = 0; kc < 2; ++kc) {
            bf16x8 af[4], bfr[4];
            #pragma unroll
            for (int mb = 0; mb < 4; ++mb) {
                int row = wm + mb * 16 + lr;
                int ch = (kc * 4 + lg) ^ (row & 7);
                af[mb] = *reinterpret_cast<const bf16x8*>(&Alds[row * 64 + ch * 8]);
            }
            #pragma unroll
            for (int nb = 0; nb < 4; ++nb) {
                int row = wn + nb * 16 + lr;
                int ch = (kc * 4 + lg) ^ (row & 7);
                bfr[nb] = *reinterpret_cast<const bf16x8*>(&Blds[row * 64 + ch * 8]);
            }
            #pragma unroll
            for (int mb = 0; mb < 4; ++mb)
                #pragma unroll
                for (int nb = 0; nb < 4; ++nb)
                    acc[mb][nb] = mfma16(af[mb], bfr[nb], acc[mb][nb]);
        }
        __syncthreads();
    }

    float bv4[4];
    #pragma unroll
    for (int nb = 0; nb < 4; ++nb) bv4[nb] = bias[tn + wn + nb * 16 + lr];

    if (z < 2) {
        bf16* Y = z == 0 ? Qo : Ko;
        #pragma unroll
        for (int mb = 0; mb < 4; ++mb)
            #pragma unroll
            for (int nb = 0; nb < 4; ++nb) {
                int col = tn + wn + nb * 16 + lr;
                #pragma unroll
                for (int r = 0; r < 4; ++r) {
                    int row = tm + wm + mb * 16 + lg * 4 + r;
                    Y[(size_t)row * H_ + col] = (bf16)(acc[mb][nb][r] + bv4[nb]);
                }
            }
    } else {
        #pragma unroll
        for (int mb = 0; mb < 4; ++mb) {
            int rowb = tm + wm + mb * 16 + lg * 4;
            #pragma unroll
            for (int nb = 0; nb < 4; ++nb) {
                int col = tn + wn + nb * 16 + lr;
                bf16x4 pk;
                #pragma unroll
                for (int r = 0; r < 4; ++r) pk[r] = (bf16)(acc[mb][nb][r] + bv4[nb]);
                *reinterpret_cast<bf16x4*>(&Vto[(size_t)col * S_ + rowb]) = pk;
            }
        }
    }
}

// ---------------- RoPE in place; Q additionally scaled by 0.125*log2e -----
__global__ __launch_bounds__(256) void rope_kernel(bf16* __restrict__ Q,
                                                   bf16* __restrict__ K,
                                                   const float2* __restrict__ tab) {
    int t = blockIdx.x * 256 + threadIdx.x;
    int i = t & 31;
    int h = (t >> 5) & 15;
    int s = (t >> 9) & 4095;
    int which = t >> 21;
    bf16* P = which ? K : Q;
    float sc = which ? 1.0f : QSCALE;
    float2 cs = tab[(s << 5) + i];
    size_t base = ((size_t)s << 10) + (h << 6) + i;
    float x1 = (float)P[base], x2 = (float)P[base + 32];
    P[base]      = (bf16)((x1 * cs.x - x2 * cs.y) * sc);
    P[base + 32] = (bf16)((x2 * cs.x + x1 * cs.y) * sc);
}

// ---------------- Flash attention, swapped-operand 32x32 structure --------
// Block: 4 waves x 32 queries = 128 q. Per KV tile (64 keys):
//   QK^T: sc = mfma32(K_frag, Q_frag)  -> lane owns query col (lane&31)
//   softmax fully in-register (defer-max THR=8, exp2 domain)
//   P -> bf16 B-frags via cvt_pk + permlane32_swap
//   PV:  O^T = mfma32(Vt_frag, P_frag) -> stays in lane=query frame
__global__ __launch_bounds__(256) void attn_kernel(
    const bf16* __restrict__ Q, const bf16* __restrict__ K, const bf16* __restrict__ Vt,
    const float* __restrict__ maskL, float* __restrict__ out)
{
    __shared__ bf16 Kl[2][64 * 64];
    __shared__ bf16 Vl[2][64 * 64];
    const int h = blockIdx.y;
    const int qb = blockIdx.x * 128;
    const int tid = threadIdx.x, lane = tid & 63, wid = tid >> 6;
    const int l31 = lane & 31, hi = lane >> 5;
    const int srow = wid * 8 + (lane >> 3);   // staging row within 32-row group
    const int ssub = lane & 7;                // staging 16B chunk

    // Q B-fragments (pre-scaled by 0.125*log2e in rope pass)
    bf16x8 qf[4];
    {
        const bf16* qp = &Q[(size_t)(qb + wid * 32 + l31) * H_ + h * 64 + hi * 8];
        #pragma unroll
        for (int ks = 0; ks < 4; ++ks)
            qf[ks] = *reinterpret_cast<const bf16x8*>(qp + ks * 16);
    }

    f32x16 o0 = {}, o1 = {};
    float m_r = -1e30f, l_r = 0.f;
    int cur = 0;

    auto STAGE = [&](int buf, int t) {
        const int kb = t * 64;
        #pragma unroll
        for (int is = 0; is < 2; ++is) {
            int row = is * 32 + srow;
            int sub = ssub ^ (row & 7);
            gload16(&K[(size_t)(kb + row) * H_ + h * 64 + sub * 8],
                    &Kl[buf][(is * 32 + wid * 8) * 64]);
            gload16(&Vt[(size_t)(h * 64 + row) * S_ + kb + sub * 8],
                    &Vl[buf][(is * 32 + wid * 8) * 64]);
        }
    };

    STAGE(0, 0);
    __syncthreads();

    for (int t = 0; t < S_ / 64; ++t) {
        if (t + 1 < S_ / 64) STAGE(cur ^ 1, t + 1);
        const int kb = t * 64;

        // ---- QK^T (swapped): sc[key][q] ----
        f32x16 sc0 = {}, sc1 = {};
        const bf16* Kb_ = Kl[cur];
        __builtin_amdgcn_s_setprio(1);
        #pragma unroll
        for (int ks = 0; ks < 4; ++ks) {
            int ch = (2 * ks + hi) ^ (l31 & 7);
            bf16x8 kf0 = *reinterpret_cast<const bf16x8*>(&Kb_[l31 * 64 + ch * 8]);
            sc0 = mfma32(kf0, qf[ks], sc0);
            bf16x8 kf1 = *reinterpret_cast<const bf16x8*>(&Kb_[(32 + l31) * 64 + ch * 8]);
            sc1 = mfma32(kf1, qf[ks], sc1);
        }
        __builtin_amdgcn_s_setprio(0);

        // ---- softmax, lane-local (32 keys here + 32 in partner lane) ----
        float p[32];
        #pragma unroll
        for (int r = 0; r < 16; ++r) p[r] = sc0[r];
        #pragma unroll
        for (int r = 0; r < 16; ++r) p[16 + r] = sc1[r];
        #pragma unroll
        for (int g = 0; g < 8; ++g) {   // p[4g+j] <-> key kb + 8g + 4hi + j
            float4 mv = *reinterpret_cast<const float4*>(&maskL[kb + g * 8 + hi * 4]);
            p[g * 4 + 0] += mv.x; p[g * 4 + 1] += mv.y;
            p[g * 4 + 2] += mv.z; p[g * 4 + 3] += mv.w;
        }
        float px = p[0];
        #pragma unroll
        for (int i = 1; i < 32; ++i) px = fmaxf(px, p[i]);
        px = fmaxf(px, __shfl_xor(px, 32, 64));

        if (__any(px - m_r > 8.0f)) {          // defer-max (T13)
            float mn = fmaxf(m_r, px);
            float corr = exp2f(m_r - mn);
            m_r = mn;
            l_r *= corr;
            #pragma unroll
            for (int r = 0; r < 16; ++r) { o0[r] *= corr; o1[r] *= corr; }
        }
        float ps = 0.f;
        #pragma unroll
        for (int i = 0; i < 32; ++i) { p[i] = exp2f(p[i] - m_r); ps += p[i]; }
        ps += __shfl_xor(ps, 32, 64);
        l_r += ps;

        // ---- P -> PV B-fragments (cvt_pk + permlane32_swap, T12) ----
        bf16x8 pf[4];
        #pragma unroll
        for (int ks = 0; ks < 4; ++ks) {
            unsigned w[4];
            #pragma unroll
            for (int wi = 0; wi < 2; ++wi) {
                unsigned u = cvtpk(p[(2 * ks) * 4 + 2 * wi], p[(2 * ks) * 4 + 2 * wi + 1]);
                unsigned v = cvtpk(p[(2 * ks + 1) * 4 + 2 * wi], p[(2 * ks + 1) * 4 + 2 * wi + 1]);
                swap32(u, v, w[wi], w[wi + 2]);
            }
            union { unsigned u[4]; bf16x8 v; } cv;
            cv.u[0] = w[0]; cv.u[1] = w[1]; cv.u[2] = w[2]; cv.u[3] = w[3];
            pf[ks] = cv.v;
        }

        // ---- PV (swapped): O^T += Vt * P^T ----
        const bf16* Vb_ = Vl[cur];
        __builtin_amdgcn_s_setprio(1);
        #pragma unroll
        for (int ks = 0; ks < 4; ++ks) {
            int ch = (2 * ks + hi) ^ (l31 & 7);
            bf16x8 vf0 = *reinterpret_cast<const bf16x8*>(&Vb_[l31 * 64 + ch * 8]);
            o0 = mfma32(vf0, pf[ks], o0);
            bf16x8 vf1 = *reinterpret_cast<const bf16x8*>(&Vb_[(32 + l31) * 64 + ch * 8]);
            o1 = mfma32(vf1, pf[ks], o1);
        }
        __builtin_amdgcn_s_setprio(0);

        __syncthreads();     // all waves done reading cur; staged cur^1 landed
        cur ^= 1;
    }

    // ---- epilogue: lane owns query qb+wid*32+l31, d = 8*g2 + 4*hi + j ----
    float inv = 1.f / l_r;
    float* orow = &out[(size_t)(qb + wid * 32 + l31) * H_ + h * 64];
    #pragma unroll
    for (int g2 = 0; g2 < 4; ++g2) {
        float4 a, b;
        a.x = o0[g2 * 4 + 0] * inv; a.y = o0[g2 * 4 + 1] * inv;
        a.z = o0[g2 * 4 + 2] * inv; a.w = o0[g2 * 4 + 3] * inv;
        b.x = o1[g2 * 4 + 0] * inv; b.y = o1[g2 * 4 + 1] * inv;
        b.z = o1[g2 * 4 + 2] * inv; b.w = o1[g2 * 4 + 3] * inv;
        *reinterpret_cast<float4*>(orow + 8 * g2 + 4 * hi) = a;
        *reinterpret_cast<float4*>(orow + 32 + 8 * g2 + 4 * hi) = b;
    }
}

extern "C" void kernel_launch(void* const* d_in, const int* in_sizes, int n_in,
                              void* d_out, int out_size, void* d_ws, size_t ws_size,
                              hipStream_t stream) {
    const float* hs   = (const float*)d_in[0];
    const float* mask = (const float*)d_in[1];
    const float* Wq   = (const float*)d_in[2];
    const float* bq   = (const float*)d_in[3];
    const float* Wk   = (const float*)d_in[4];
    const float* bk   = (const float*)d_in[5];
    const float* Wv   = (const float*)d_in[6];
    const float* bv   = (const float*)d_in[7];
    float* out = (float*)d_out;

    char* ws = (char*)d_ws;
    bf16* Xb    = (bf16*)(ws);                  // 8 MB  [S,H]
    bf16* Wqb   = (bf16*)(ws + (8u  << 20));    // 2 MB
    bf16* Wkb   = (bf16*)(ws + (10u << 20));    // 2 MB
    bf16* Wvb   = (bf16*)(ws + (12u << 20));    // 2 MB
    bf16* Qb    = (bf16*)(ws + (14u << 20));    // 8 MB  [S,H]
    bf16* Kb    = (bf16*)(ws + (22u << 20));    // 8 MB  [S,H]
    bf16* Vt    = (bf16*)(ws + (30u << 20));    // 8 MB  [H,S]
    float2* tab = (float2*)(ws + (38u << 20));  // 1 MB  [S,32]
    float* maskL = (float*)(ws + (39u << 20));  // 16 KB

    cvt_kernel<<<S_ * H_ / 2048, 256, 0, stream>>>(hs, Xb, S_ * H_);
    cvt_kernel<<<H_ * H_ / 2048, 256, 0, stream>>>(Wq, Wqb, H_ * H_);
    cvt_kernel<<<H_ * H_ / 2048, 256, 0, stream>>>(Wk, Wkb, H_ * H_);
    cvt_kernel<<<H_ * H_ / 2048, 256, 0, stream>>>(Wv, Wvb, H_ * H_);
    rope_table_kernel<<<(S_ * 32) / 256, 256, 0, stream>>>(tab);
    maskl_kernel<<<(S_ + 255) / 256, 256, 0, stream>>>(mask, maskL);
    qkv_gemm_kernel<<<dim3(H_ / 128, S_ / 128, 3), 256, 0, stream>>>(
        Xb, Wqb, Wkb, Wvb, bq, bk, bv, Qb, Kb, Vt);
    rope_kernel<<<(2 * S_ * NH_ * 32) / 256, 256, 0, stream>>>(Qb, Kb, tab);
    attn_kernel<<<dim3(S_ / 128, NH_), 256, 0, stream>>>(Qb, Kb, Vt, maskL, out);
}